// Round 6
// baseline (164.690 us; speedup 1.0000x reference)
//
#include <hip/hip_runtime.h>

#define T_DIM 8192
#define NTH 1024
#define NWAVE 16
#define GROUPS 2
#define KEEP_K 2867                 // max(1, round(8192 * 0.35))
#define KSCALE 32768.0f             // 16-bit fixed-point key scale (scores < 2.0)
#define INV_KSCALE (1.0f / 32768.0f)

typedef float nt4 __attribute__((ext_vector_type(4)));  // native vec for nontemporal store

// Scan 256-bin histogram from the top, find digit where cumulative count
// reaches k. Executed by wave 0 only.
__device__ __forceinline__ void scan_top256(const unsigned* bins, unsigned k, int lane,
                                            unsigned* sh_digit, unsigned* sh_k) {
    const int r0 = lane * 4;
    const unsigned c0 = bins[255 - r0];
    const unsigned c1 = bins[255 - (r0 + 1)];
    const unsigned c2 = bins[255 - (r0 + 2)];
    const unsigned c3 = bins[255 - (r0 + 3)];
    const unsigned s1 = c0 + c1, s2 = s1 + c2, s3 = s2 + c3;
    unsigned tot = s3;
    #pragma unroll
    for (int off = 1; off < 64; off <<= 1) {
        const unsigned n = __shfl_up(tot, off, 64);
        if (lane >= off) tot += n;
    }
    const unsigned excl = tot - s3;
    const unsigned Pc[4] = { excl + c0, excl + s1, excl + s2, excl + s3 };
    unsigned prev = excl;
    #pragma unroll
    for (int c = 0; c < 4; ++c) {
        if (Pc[c] >= k && prev < k) {
            *sh_digit = (unsigned)(255 - (r0 + c));
            *sh_k = k - prev;
        }
        prev = Pc[c];
    }
}

// NO occupancy hint: every explicit occupancy request at 1024 thr
// ((1024,8) and amdgpu_waves_per_eu(8)) collapsed the allocator to 32 VGPR
// and spilled all state (rounds 1/3/4). Plain (1024) lets it allocate what
// the 16-float state needs (~40-56); if that lands <=64 we get 2 blocks/CU
// = 32 waves/CU; if not, 1 block/CU = the same 50% ceiling as the 512 shape.
__global__ __launch_bounds__(NTH) void srp_kernel(
    const float* __restrict__ g_anchor,
    const float* __restrict__ g_lr,
    const float* __restrict__ g_pw,
    const float* __restrict__ g_bl,
    const float* __restrict__ g_mask,
    const float* __restrict__ g_sbud,
    const float* __restrict__ g_pbud,
    const float* __restrict__ g_psp,
    const float* __restrict__ g_ppa,
    const int*  __restrict__ g_front,
    float* __restrict__ g_out,
    int n_rows)
{
    constexpr float MIN_SPEECH = 1.0f;
    constexpr float MAX_EXPAND = 3.0f;
    constexpr float MIN_BW = 0.1f;
    constexpr float BIAS_W = 0.15f;
    constexpr float INV_TEMP = 1.0f / 0.12f;

    __shared__ unsigned ku[T_DIM / 2];          // 16 KB: packed 16-bit keys
    __shared__ unsigned hist[NWAVE][256];       // 16 KB: per-wave histograms
    __shared__ unsigned s_tot[256];
    __shared__ float wred[NWAVE][4];
    __shared__ float s_scal[6];
    __shared__ unsigned sh_hb, sh_k1, sh_lb, sh_k2;

    const int b = blockIdx.x;
    const int tid = threadIdx.x;
    const int wave = tid >> 6;
    const int lane = tid & 63;
    const long long row = (long long)b * T_DIM;
    const int f = g_front[b];

    // zero this wave's own histogram (wave-private -> no barrier needed)
    #pragma unroll
    for (int d = 0; d < 4; ++d) hist[wave][lane + 64 * d] = 0u;

    // Minimal per-thread state (16 floats):
    //  SC1[i]: pre? ps*m^2 : cand*tail*m        (speech value pre-scale)
    //  PM[i]:  pre? pp*m^2 : m                  (pause prefix output, or mask;
    //          pass 2 overwrites tail entries with tc*tail*m)
    float SC1[8];
    float PM[8];
    float a_ps = 0.f, a_pp = 0.f, a_ts = 0.f, a_cs = 0.f;

    // ---------- Pass 1 ----------
    // Traffic cut (round-5 win): psp/ppa contribute ONLY where t < f;
    // anchor/lr contribute ONLY where t >= f. Loads skipped per 4-elem group
    // outside their live region (exec-masked, contiguous).
    #pragma unroll
    for (int g = 0; g < GROUPS; ++g) {
        const int t0 = g * 4096 + (tid << 2);
        float m_[4], tl_[4];
        // phase a: mask (always) + previous-exec streams (prefix only)
        {
            const float4 mk4 = *reinterpret_cast<const float4*>(g_mask + row + t0);
            float4 ps4 = {0.f, 0.f, 0.f, 0.f};
            float4 pp4 = {0.f, 0.f, 0.f, 0.f};
            if (t0 < f) {   // group touches the prefix region
                ps4 = *reinterpret_cast<const float4*>(g_psp + row + t0);
                pp4 = *reinterpret_cast<const float4*>(g_ppa + row + t0);
            }
            #pragma unroll
            for (int c = 0; c < 4; ++c) {
                const int i = (g << 2) + c;
                const int t = t0 + c;
                const float m = (&mk4.x)[c];
                const bool pre = (t < f);
                const float tail = pre ? 0.0f : m;
                const float ps = (&ps4.x)[c];
                const float pp = (&pp4.x)[c];
                if (pre) { a_ps += ps * m; a_pp += pp * m; }
                a_ts += tail;
                SC1[i] = pre ? ps * m * m : 0.0f;
                PM[i]  = pre ? pp * m * m : m;
                m_[c] = m; tl_[c] = tail;
            }
        }
        // phase b: speech candidate streams (tail only)
        if (t0 + 3 >= f) {  // group touches the tail region
            const float4 an4 = *reinterpret_cast<const float4*>(g_anchor + row + t0);
            const float4 lr4 = *reinterpret_cast<const float4*>(g_lr + row + t0);
            #pragma unroll
            for (int c = 0; c < 4; ++c) {
                const int i = (g << 2) + c;
                const float an = fmaxf((&an4.x)[c], MIN_SPEECH);
                const float cand = fminf(fmaxf(an * __expf((&lr4.x)[c]), MIN_SPEECH),
                                         an * MAX_EXPAND) * m_[c];
                a_cs += cand * tl_[c];
                SC1[i] += cand * tl_[c] * m_[c];
            }
        }
        // phase c: score streams -> packed keys + pass-A histogram (always)
        {
            const float4 pw4 = *reinterpret_cast<const float4*>(g_pw + row + t0);
            const float4 bl4 = *reinterpret_cast<const float4*>(g_bl + row + t0);
            unsigned kk0 = 0u, kk1 = 0u;
            #pragma unroll
            for (int c = 0; c < 4; ++c) {
                const float s = (fmaxf((&pw4.x)[c], 0.0f)
                                 + BIAS_W * (MIN_BW + fmaxf((&bl4.x)[c], 0.0f))) * m_[c];
                const unsigned key = (unsigned)fminf(s * KSCALE, 65535.0f);
                atomicAdd(&hist[wave][key >> 8], 1u);
                if (c < 2) kk0 |= key << (16 * c);
                else       kk1 |= key << (16 * (c - 2));
            }
            uint2 w2; w2.x = kk0; w2.y = kk1;
            *reinterpret_cast<uint2*>(&ku[t0 >> 1]) = w2;
        }
    }

    // wave-level reduce of the 4 accumulators
    #pragma unroll
    for (int o = 32; o > 0; o >>= 1) {
        a_ps += __shfl_down(a_ps, o, 64);
        a_pp += __shfl_down(a_pp, o, 64);
        a_ts += __shfl_down(a_ts, o, 64);
        a_cs += __shfl_down(a_cs, o, 64);
    }
    if (lane == 0) {
        wred[wave][0] = a_ps; wred[wave][1] = a_pp;
        wred[wave][2] = a_ts; wred[wave][3] = a_cs;
    }
    __syncthreads();                                                    // B1

    if (tid < 256) {
        unsigned s = 0;
        #pragma unroll
        for (int w = 0; w < NWAVE; ++w) s += hist[w][tid];
        s_tot[tid] = s;
    }
    if (tid == 0) {
        float ps = 0.f, pp = 0.f, ts = 0.f, cs = 0.f;
        for (int w = 0; w < NWAVE; ++w) {
            ps += wred[w][0]; pp += wred[w][1];
            ts += wred[w][2]; cs += wred[w][3];
        }
        const float sb = fmaxf(g_sbud[b], ps + ts * MIN_SPEECH);
        const float pb = fmaxf(g_pbud[b], pp);
        const float rem_s = sb - ps;
        const float cts = fmaxf(cs, 1e-6f);
        s_scal[0] = (ts > 0.0f && rem_s > 0.0f) ? (rem_s / cts) : 0.0f;  // scale_s
        s_scal[1] = fmaxf(pb - pp, 0.0f);                                // rem_p
        s_scal[2] = ts;
        s_scal[3] = fmaxf(ts, 1.0f);
    }
    __syncthreads();                                                    // B2

    // wave0 scans pass-A first so the other 15 waves' speech stores overlap it
    if (wave == 0) scan_top256(s_tot, KEEP_K, lane, &sh_hb, &sh_k1);

    // ---- early speech store: only needs scale_s; overlaps the selection ----
    {
        const float scale_s = s_scal[0];
        #pragma unroll
        for (int g = 0; g < GROUPS; ++g) {
            const int t0 = g * 4096 + (tid << 2);
            nt4 vs;
            #pragma unroll
            for (int c = 0; c < 4; ++c) {
                const int i = (g << 2) + c;
                const int t = t0 + c;
                vs[c] = (t < f) ? SC1[i] : SC1[i] * scale_s;
            }
            __builtin_nontemporal_store(vs, reinterpret_cast<nt4*>(g_out + row + t0));
        }
    }
    // re-zero own histogram for pass B
    #pragma unroll
    for (int d = 0; d < 4; ++d) hist[wave][lane + 64 * d] = 0u;
    __syncthreads();                                                    // B3

    // ---------- Pass B: low-byte histogram within selected high-byte bucket ----------
    const unsigned hb = sh_hb;
    #pragma unroll
    for (int g = 0; g < GROUPS; ++g) {
        const int t0 = g * 4096 + (tid << 2);
        const uint2 w2 = *reinterpret_cast<const uint2*>(&ku[t0 >> 1]);
        const unsigned k0 = w2.x & 0xFFFFu, k1 = w2.x >> 16;
        const unsigned k2 = w2.y & 0xFFFFu, k3 = w2.y >> 16;
        if ((k0 >> 8) == hb) atomicAdd(&hist[wave][k0 & 0xFFu], 1u);
        if ((k1 >> 8) == hb) atomicAdd(&hist[wave][k1 & 0xFFu], 1u);
        if ((k2 >> 8) == hb) atomicAdd(&hist[wave][k2 & 0xFFu], 1u);
        if ((k3 >> 8) == hb) atomicAdd(&hist[wave][k3 & 0xFFu], 1u);
    }
    __syncthreads();                                                    // B4
    if (tid < 256) {
        unsigned s = 0;
        #pragma unroll
        for (int w = 0; w < NWAVE; ++w) s += hist[w][tid];
        s_tot[tid] = s;
    }
    __syncthreads();                                                    // B5
    if (wave == 0) scan_top256(s_tot, sh_k1, lane, &sh_lb, &sh_k2);
    __syncthreads();                                                    // B6

    const float thr = (float)((sh_hb << 8) | sh_lb) * INV_KSCALE;

    // ---------- Pass 2: gated denominator (scores reconstructed from keys) ----------
    // Only tail elements (t >= f) contribute; prefix work skipped entirely.
    const float inv_ts6 = 1e-6f / s_scal[3];
    float a_d = 0.0f;
    #pragma unroll
    for (int g = 0; g < GROUPS; ++g) {
        const int t0 = g * 4096 + (tid << 2);
        if (t0 + 3 < f) continue;   // whole group is prefix
        const uint2 w2 = *reinterpret_cast<const uint2*>(&ku[t0 >> 1]);
        const unsigned kk[4] = { w2.x & 0xFFFFu, w2.x >> 16, w2.y & 0xFFFFu, w2.y >> 16 };
        #pragma unroll
        for (int c = 0; c < 4; ++c) {
            const int i = (g << 2) + c;
            const int t = t0 + c;
            if (t >= f) {
                const float m = PM[i];                     // tail = m (pre==0)
                const float s = (float)kk[c] * INV_KSCALE;
                const float gate = 1.0f / (1.0f + __expf(-(s - thr) * INV_TEMP));
                const float tc = s * gate * m * m + m * inv_ts6;   // tail_cand
                a_d += tc * m;                             // tc * tail
                PM[i] = tc * m * m;                        // tc * tail * m
            }
        }
    }
    #pragma unroll
    for (int o = 32; o > 0; o >>= 1) a_d += __shfl_down(a_d, o, 64);
    if (lane == 0) wred[wave][0] = a_d;
    __syncthreads();                                                    // B7
    if (tid == 0) {
        float d = 0.f;
        for (int w = 0; w < NWAVE; ++w) d += wred[w][0];
        const float denom = fmaxf(d, 1e-6f);
        const float ts = s_scal[2];
        const float rem_p = s_scal[1];
        s_scal[4] = (ts > 0.0f && rem_p > 0.0f) ? (rem_p / denom) : 0.0f;  // scale_p
    }
    __syncthreads();                                                    // B8

    // ---------- pause store ----------
    const float scale_p = s_scal[4];
    const long long out_off = (long long)n_rows * T_DIM;
    #pragma unroll
    for (int g = 0; g < GROUPS; ++g) {
        const int t0 = g * 4096 + (tid << 2);
        nt4 vp;
        #pragma unroll
        for (int c = 0; c < 4; ++c) {
            const int i = (g << 2) + c;
            const int t = t0 + c;
            vp[c] = (t < f) ? PM[i] : PM[i] * scale_p;
        }
        __builtin_nontemporal_store(vp, reinterpret_cast<nt4*>(g_out + out_off + row + t0));
    }
}

extern "C" void kernel_launch(void* const* d_in, const int* in_sizes, int n_in,
                              void* d_out, int out_size, void* d_ws, size_t ws_size,
                              hipStream_t stream) {
    const float* anchor = (const float*)d_in[0];
    const float* lr     = (const float*)d_in[1];
    const float* pw     = (const float*)d_in[2];
    const float* bl     = (const float*)d_in[3];
    const float* mask   = (const float*)d_in[4];
    const float* sbud   = (const float*)d_in[5];
    const float* pbud   = (const float*)d_in[6];
    const float* psp    = (const float*)d_in[7];
    const float* ppa    = (const float*)d_in[8];
    const int*   front  = (const int*)d_in[9];
    float* out = (float*)d_out;
    const int B = in_sizes[5];   // speech_budget_win has B elements
    srp_kernel<<<B, NTH, 0, stream>>>(anchor, lr, pw, bl, mask, sbud, pbud,
                                      psp, ppa, front, out, B);
}

// Round 7
// 163.950 us; speedup vs baseline: 1.0045x; 1.0045x over previous
//
#include <hip/hip_runtime.h>

#define T_DIM 8192
#define NTH 1024
#define NWAVE 16
#define GROUPS 2
#define KEEP_K 2867                 // max(1, round(8192 * 0.35))
#define KSCALE 32768.0f             // 16-bit fixed-point key scale (scores < 2.0)
#define INV_KSCALE (1.0f / 32768.0f)

typedef float nt4 __attribute__((ext_vector_type(4)));  // native vec for nontemporal store

// Register-bin scan executed by wave 0: lane L holds totals for bins
// 255-4L .. 255-4L-3 (scan order from the top); finds digit where the
// cumulative count reaches k.
__device__ __forceinline__ void scan_top256_reg(unsigned c0, unsigned c1,
                                                unsigned c2, unsigned c3,
                                                unsigned k, int lane,
                                                unsigned* sh_digit, unsigned* sh_k) {
    const int r0 = lane * 4;
    const unsigned s1 = c0 + c1, s2 = s1 + c2, s3 = s2 + c3;
    unsigned tot = s3;
    #pragma unroll
    for (int off = 1; off < 64; off <<= 1) {
        const unsigned n = __shfl_up(tot, off, 64);
        if (lane >= off) tot += n;
    }
    const unsigned excl = tot - s3;
    const unsigned Pc[4] = { excl + c0, excl + s1, excl + s2, excl + s3 };
    unsigned prev = excl;
    #pragma unroll
    for (int c = 0; c < 4; ++c) {
        if (Pc[c] >= k && prev < k) {
            *sh_digit = (unsigned)(255 - (r0 + c));
            *sh_k = k - prev;
        }
        prev = Pc[c];
    }
}

// Plain __launch_bounds__(1024): any explicit occupancy request at 1024 thr
// collapsed the allocator to 32 VGPR + full spill (rounds 1/3/4). Plain form
// gives VGPR=48, no spill (round 6).
__global__ __launch_bounds__(NTH) void srp_kernel(
    const float* __restrict__ g_anchor,
    const float* __restrict__ g_lr,
    const float* __restrict__ g_pw,
    const float* __restrict__ g_bl,
    const float* __restrict__ g_mask,
    const float* __restrict__ g_sbud,
    const float* __restrict__ g_pbud,
    const float* __restrict__ g_psp,
    const float* __restrict__ g_ppa,
    const int*  __restrict__ g_front,
    float* __restrict__ g_out,
    int n_rows)
{
    constexpr float MIN_SPEECH = 1.0f;
    constexpr float MAX_EXPAND = 3.0f;
    constexpr float MIN_BW = 0.1f;
    constexpr float BIAS_W = 0.15f;
    constexpr float INV_TEMP = 1.0f / 0.12f;

    __shared__ unsigned ku[T_DIM / 2];          // 16 KB: packed 16-bit keys
    __shared__ unsigned hist[NWAVE][256];       // 16 KB: per-wave histograms
    __shared__ float wred[NWAVE][4];
    __shared__ unsigned sh_hb, sh_k1, sh_lb, sh_k2;

    const int b = blockIdx.x;
    const int tid = threadIdx.x;
    const int wave = tid >> 6;
    const int lane = tid & 63;
    const long long row = (long long)b * T_DIM;
    const int f = g_front[b];

    // zero this wave's own histogram (wave-private -> no barrier needed)
    #pragma unroll
    for (int d = 0; d < 4; ++d) hist[wave][lane + 64 * d] = 0u;

    // Minimal per-thread state (16 floats):
    //  SC1[i]: pre? ps*m^2 : cand*tail*m        (speech value pre-scale)
    //  PM[i]:  pre? pp*m^2 : m                  (pause prefix output, or mask;
    //          pass 2 overwrites tail entries with tc*tail*m)
    float SC1[8];
    float PM[8];
    float a_ps = 0.f, a_pp = 0.f, a_ts = 0.f, a_cs = 0.f;

    // ---------- Pass 1 ----------
    // Traffic cut (round-5 win): psp/ppa contribute ONLY where t < f;
    // anchor/lr contribute ONLY where t >= f. Loads skipped per 4-elem group
    // outside their live region.
    #pragma unroll
    for (int g = 0; g < GROUPS; ++g) {
        const int t0 = g * 4096 + (tid << 2);
        float m_[4], tl_[4];
        // phase a: mask (always) + previous-exec streams (prefix only)
        {
            const float4 mk4 = *reinterpret_cast<const float4*>(g_mask + row + t0);
            float4 ps4 = {0.f, 0.f, 0.f, 0.f};
            float4 pp4 = {0.f, 0.f, 0.f, 0.f};
            if (t0 < f) {
                ps4 = *reinterpret_cast<const float4*>(g_psp + row + t0);
                pp4 = *reinterpret_cast<const float4*>(g_ppa + row + t0);
            }
            #pragma unroll
            for (int c = 0; c < 4; ++c) {
                const int i = (g << 2) + c;
                const int t = t0 + c;
                const float m = (&mk4.x)[c];
                const bool pre = (t < f);
                const float tail = pre ? 0.0f : m;
                const float ps = (&ps4.x)[c];
                const float pp = (&pp4.x)[c];
                if (pre) { a_ps += ps * m; a_pp += pp * m; }
                a_ts += tail;
                SC1[i] = pre ? ps * m * m : 0.0f;
                PM[i]  = pre ? pp * m * m : m;
                m_[c] = m; tl_[c] = tail;
            }
        }
        // phase b: speech candidate streams (tail only)
        if (t0 + 3 >= f) {
            const float4 an4 = *reinterpret_cast<const float4*>(g_anchor + row + t0);
            const float4 lr4 = *reinterpret_cast<const float4*>(g_lr + row + t0);
            #pragma unroll
            for (int c = 0; c < 4; ++c) {
                const int i = (g << 2) + c;
                const float an = fmaxf((&an4.x)[c], MIN_SPEECH);
                const float cand = fminf(fmaxf(an * __expf((&lr4.x)[c]), MIN_SPEECH),
                                         an * MAX_EXPAND) * m_[c];
                a_cs += cand * tl_[c];
                SC1[i] += cand * tl_[c] * m_[c];
            }
        }
        // phase c: score streams -> packed keys + pass-A histogram (always)
        {
            const float4 pw4 = *reinterpret_cast<const float4*>(g_pw + row + t0);
            const float4 bl4 = *reinterpret_cast<const float4*>(g_bl + row + t0);
            unsigned kk0 = 0u, kk1 = 0u;
            #pragma unroll
            for (int c = 0; c < 4; ++c) {
                const float s = (fmaxf((&pw4.x)[c], 0.0f)
                                 + BIAS_W * (MIN_BW + fmaxf((&bl4.x)[c], 0.0f))) * m_[c];
                const unsigned key = (unsigned)fminf(s * KSCALE, 65535.0f);
                atomicAdd(&hist[wave][key >> 8], 1u);
                if (c < 2) kk0 |= key << (16 * c);
                else       kk1 |= key << (16 * (c - 2));
            }
            uint2 w2; w2.x = kk0; w2.y = kk1;
            *reinterpret_cast<uint2*>(&ku[t0 >> 1]) = w2;
        }
    }

    // wave-level reduce of the 4 accumulators
    #pragma unroll
    for (int o = 32; o > 0; o >>= 1) {
        a_ps += __shfl_down(a_ps, o, 64);
        a_pp += __shfl_down(a_pp, o, 64);
        a_ts += __shfl_down(a_ts, o, 64);
        a_cs += __shfl_down(a_cs, o, 64);
    }
    if (lane == 0) {
        wred[wave][0] = a_ps; wred[wave][1] = a_pp;
        wred[wave][2] = a_ts; wred[wave][3] = a_cs;
    }
    __syncthreads();                                                    // B1

    // ---- ALL waves redundantly compute block totals + scales (uniform) ----
    // lane L reads wred[L&15][L>>4]; xor-reduce over the 16-lane group sums
    // the 16 wave partials; lanes 0/16/32/48 hold ps/pp/ts/cs.
    float bv = wred[lane & 15][lane >> 4];
    bv += __shfl_xor(bv, 8, 64);
    bv += __shfl_xor(bv, 4, 64);
    bv += __shfl_xor(bv, 2, 64);
    bv += __shfl_xor(bv, 1, 64);
    const float ps_t = __shfl(bv, 0, 64);
    const float pp_t = __shfl(bv, 16, 64);
    const float ts_t = __shfl(bv, 32, 64);
    const float cs_t = __shfl(bv, 48, 64);
    const float sb = fmaxf(g_sbud[b], ps_t + ts_t * MIN_SPEECH);
    const float pb = fmaxf(g_pbud[b], pp_t);
    const float rem_s = sb - ps_t;
    const float scale_s = (ts_t > 0.0f && rem_s > 0.0f)
                              ? (rem_s / fmaxf(cs_t, 1e-6f)) : 0.0f;
    const float rem_p = fmaxf(pb - pp_t, 0.0f);
    const float inv_ts6 = 1e-6f / fmaxf(ts_t, 1.0f);

    if (wave == 0) {
        // sum the 16 wave histograms for my 4 scan-order bins, then scan A.
        const int r0 = lane * 4;
        unsigned c0 = 0, c1 = 0, c2 = 0, c3 = 0;
        #pragma unroll
        for (int w = 0; w < NWAVE; ++w) {
            c0 += hist[w][255 - r0];
            c1 += hist[w][255 - (r0 + 1)];
            c2 += hist[w][255 - (r0 + 2)];
            c3 += hist[w][255 - (r0 + 3)];
        }
        scan_top256_reg(c0, c1, c2, c3, KEEP_K, lane, &sh_hb, &sh_k1);
    } else {
        // waves 1..15: speech store overlaps wave-0's scan A
        #pragma unroll
        for (int g = 0; g < GROUPS; ++g) {
            const int t0 = g * 4096 + (tid << 2);
            nt4 vs;
            #pragma unroll
            for (int c = 0; c < 4; ++c) {
                const int i = (g << 2) + c;
                const int t = t0 + c;
                vs[c] = (t < f) ? SC1[i] : SC1[i] * scale_s;
            }
            __builtin_nontemporal_store(vs, reinterpret_cast<nt4*>(g_out + row + t0));
        }
    }
    __syncthreads();                                                    // B2

    // wave 0's deferred speech store
    if (wave == 0) {
        #pragma unroll
        for (int g = 0; g < GROUPS; ++g) {
            const int t0 = g * 4096 + (tid << 2);
            nt4 vs;
            #pragma unroll
            for (int c = 0; c < 4; ++c) {
                const int i = (g << 2) + c;
                const int t = t0 + c;
                vs[c] = (t < f) ? SC1[i] : SC1[i] * scale_s;
            }
            __builtin_nontemporal_store(vs, reinterpret_cast<nt4*>(g_out + row + t0));
        }
    }
    // re-zero own histogram (safe: scan A finished before B2), then pass B.
    #pragma unroll
    for (int d = 0; d < 4; ++d) hist[wave][lane + 64 * d] = 0u;

    // ---------- Pass B: low-byte histogram within selected high-byte bucket ----------
    const unsigned hb = sh_hb;
    #pragma unroll
    for (int g = 0; g < GROUPS; ++g) {
        const int t0 = g * 4096 + (tid << 2);
        const uint2 w2 = *reinterpret_cast<const uint2*>(&ku[t0 >> 1]);
        const unsigned k0 = w2.x & 0xFFFFu, k1 = w2.x >> 16;
        const unsigned k2 = w2.y & 0xFFFFu, k3 = w2.y >> 16;
        if ((k0 >> 8) == hb) atomicAdd(&hist[wave][k0 & 0xFFu], 1u);
        if ((k1 >> 8) == hb) atomicAdd(&hist[wave][k1 & 0xFFu], 1u);
        if ((k2 >> 8) == hb) atomicAdd(&hist[wave][k2 & 0xFFu], 1u);
        if ((k3 >> 8) == hb) atomicAdd(&hist[wave][k3 & 0xFFu], 1u);
    }
    __syncthreads();                                                    // B3

    if (wave == 0) {
        // sum + scan B
        const int r0 = lane * 4;
        unsigned c0 = 0, c1 = 0, c2 = 0, c3 = 0;
        #pragma unroll
        for (int w = 0; w < NWAVE; ++w) {
            c0 += hist[w][255 - r0];
            c1 += hist[w][255 - (r0 + 1)];
            c2 += hist[w][255 - (r0 + 2)];
            c3 += hist[w][255 - (r0 + 3)];
        }
        scan_top256_reg(c0, c1, c2, c3, sh_k1, lane, &sh_lb, &sh_k2);
    } else {
        // store fully-prefix pause groups (PM = pp*m^2, independent of scale_p)
        #pragma unroll
        for (int g = 0; g < GROUPS; ++g) {
            const int t0 = g * 4096 + (tid << 2);
            if (t0 + 3 < f) {
                nt4 vp;
                #pragma unroll
                for (int c = 0; c < 4; ++c) vp[c] = PM[(g << 2) + c];
                __builtin_nontemporal_store(
                    vp, reinterpret_cast<nt4*>(g_out + (long long)n_rows * T_DIM + row + t0));
            }
        }
    }
    __syncthreads();                                                    // B4

    const float thr = (float)((sh_hb << 8) | sh_lb) * INV_KSCALE;

    // ---------- Pass 2: gated denominator (scores reconstructed from keys) ----------
    float a_d = 0.0f;
    #pragma unroll
    for (int g = 0; g < GROUPS; ++g) {
        const int t0 = g * 4096 + (tid << 2);
        if (t0 + 3 < f) continue;   // whole group is prefix
        const uint2 w2 = *reinterpret_cast<const uint2*>(&ku[t0 >> 1]);
        const unsigned kk[4] = { w2.x & 0xFFFFu, w2.x >> 16, w2.y & 0xFFFFu, w2.y >> 16 };
        #pragma unroll
        for (int c = 0; c < 4; ++c) {
            const int i = (g << 2) + c;
            const int t = t0 + c;
            if (t >= f) {
                const float m = PM[i];                     // tail = m (pre==0)
                const float s = (float)kk[c] * INV_KSCALE;
                const float gate = 1.0f / (1.0f + __expf(-(s - thr) * INV_TEMP));
                const float tc = s * gate * m * m + m * inv_ts6;   // tail_cand
                a_d += tc * m;                             // tc * tail
                PM[i] = tc * m * m;                        // tc * tail * m
            }
        }
    }
    #pragma unroll
    for (int o = 32; o > 0; o >>= 1) a_d += __shfl_down(a_d, o, 64);
    if (lane == 0) wred[wave][0] = a_d;
    __syncthreads();                                                    // B5

    // ---- ALL waves redundantly compute scale_p (uniform; no extra barrier) ----
    float dv = (lane < 16) ? wred[lane][0] : 0.0f;
    dv += __shfl_xor(dv, 8, 64);
    dv += __shfl_xor(dv, 4, 64);
    dv += __shfl_xor(dv, 2, 64);
    dv += __shfl_xor(dv, 1, 64);
    const float denom = fmaxf(__shfl(dv, 0, 64), 1e-6f);
    const float scale_p = (ts_t > 0.0f && rem_p > 0.0f) ? (rem_p / denom) : 0.0f;

    // ---------- pause store (tail + boundary; wave 0 also its prefix groups) ----------
    const long long out_off = (long long)n_rows * T_DIM;
    #pragma unroll
    for (int g = 0; g < GROUPS; ++g) {
        const int t0 = g * 4096 + (tid << 2);
        if (wave != 0 && t0 + 3 < f) continue;   // already stored during scan B
        nt4 vp;
        #pragma unroll
        for (int c = 0; c < 4; ++c) {
            const int i = (g << 2) + c;
            const int t = t0 + c;
            vp[c] = (t < f) ? PM[i] : PM[i] * scale_p;
        }
        __builtin_nontemporal_store(vp, reinterpret_cast<nt4*>(g_out + out_off + row + t0));
    }
}

extern "C" void kernel_launch(void* const* d_in, const int* in_sizes, int n_in,
                              void* d_out, int out_size, void* d_ws, size_t ws_size,
                              hipStream_t stream) {
    const float* anchor = (const float*)d_in[0];
    const float* lr     = (const float*)d_in[1];
    const float* pw     = (const float*)d_in[2];
    const float* bl     = (const float*)d_in[3];
    const float* mask   = (const float*)d_in[4];
    const float* sbud   = (const float*)d_in[5];
    const float* pbud   = (const float*)d_in[6];
    const float* psp    = (const float*)d_in[7];
    const float* ppa    = (const float*)d_in[8];
    const int*   front  = (const int*)d_in[9];
    float* out = (float*)d_out;
    const int B = in_sizes[5];   // speech_budget_win has B elements
    srp_kernel<<<B, NTH, 0, stream>>>(anchor, lr, pw, bl, mask, sbud, pbud,
                                      psp, ppa, front, out, B);
}

// Round 9
// 161.707 us; speedup vs baseline: 1.0184x; 1.0139x over previous
//
#include <hip/hip_runtime.h>

#define T_DIM 8192
#define NTH 512
#define NWAVE 8
#define GROUPS 4
#define KEEP_K 2867                 // max(1, round(8192 * 0.35))
#define KSCALE 32768.0f             // 16-bit fixed-point key scale (scores < 2.0)
#define INV_KSCALE (1.0f / 32768.0f)

typedef float nt4 __attribute__((ext_vector_type(4)));  // native vec for nontemporal store

// Scan 256-bin histogram from the top, find digit where cumulative count
// reaches k. Executed by wave 0 only.
__device__ __forceinline__ void scan_top256(const unsigned* bins, unsigned k, int lane,
                                            unsigned* sh_digit, unsigned* sh_k) {
    const int r0 = lane * 4;
    const unsigned c0 = bins[255 - r0];
    const unsigned c1 = bins[255 - (r0 + 1)];
    const unsigned c2 = bins[255 - (r0 + 2)];
    const unsigned c3 = bins[255 - (r0 + 3)];
    const unsigned s1 = c0 + c1, s2 = s1 + c2, s3 = s2 + c3;
    unsigned tot = s3;
    #pragma unroll
    for (int off = 1; off < 64; off <<= 1) {
        const unsigned n = __shfl_up(tot, off, 64);
        if (lane >= off) tot += n;
    }
    const unsigned excl = tot - s3;
    const unsigned Pc[4] = { excl + c0, excl + s1, excl + s2, excl + s3 };
    unsigned prev = excl;
    #pragma unroll
    for (int c = 0; c < 4; ++c) {
        if (Pc[c] >= k && prev < k) {
            *sh_digit = (unsigned)(255 - (r0 + c));
            *sh_k = k - prev;
        }
        prev = Pc[c];
    }
}

// Issue ALL live streams of group gg back-to-back (unphased -> max loads in
// flight). Skipped regions (round-5 traffic win) get benign constants so the
// unguarded parts of compute stay NaN-free.
#define LOADG(gg, mk4, ps4, pp4, an4, lr4, pw4, bl4)                           \
    {                                                                          \
        const int t0 = (gg) * 2048 + (tid << 2);                               \
        mk4 = *reinterpret_cast<const float4*>(g_mask + row + t0);             \
        ps4 = make_float4(0.f, 0.f, 0.f, 0.f);                                 \
        pp4 = make_float4(0.f, 0.f, 0.f, 0.f);                                 \
        an4 = make_float4(1.f, 1.f, 1.f, 1.f);                                 \
        lr4 = make_float4(0.f, 0.f, 0.f, 0.f);                                 \
        if (t0 < f) {                                                          \
            ps4 = *reinterpret_cast<const float4*>(g_psp + row + t0);          \
            pp4 = *reinterpret_cast<const float4*>(g_ppa + row + t0);          \
        }                                                                      \
        if (t0 + 3 >= f) {                                                     \
            an4 = *reinterpret_cast<const float4*>(g_anchor + row + t0);       \
            lr4 = *reinterpret_cast<const float4*>(g_lr + row + t0);           \
        }                                                                      \
        pw4 = *reinterpret_cast<const float4*>(g_pw + row + t0);               \
        bl4 = *reinterpret_cast<const float4*>(g_bl + row + t0);               \
    }

// Consume one group's buffers; identical math/order to the round-5 kernel.
#define COMPUTE(gg, mk4, ps4, pp4, an4, lr4, pw4, bl4)                         \
    {                                                                          \
        const int t0 = (gg) * 2048 + (tid << 2);                               \
        float m_[4], tl_[4];                                                   \
        _Pragma("unroll")                                                      \
        for (int c = 0; c < 4; ++c) {                                          \
            const int i = ((gg) << 2) + c;                                     \
            const int t = t0 + c;                                              \
            const float m = (&mk4.x)[c];                                       \
            const bool pre = (t < f);                                          \
            const float tail = pre ? 0.0f : m;                                 \
            const float ps = (&ps4.x)[c];                                      \
            const float pp = (&pp4.x)[c];                                      \
            if (pre) { a_ps += ps * m; a_pp += pp * m; }                       \
            a_ts += tail;                                                      \
            SC1[i] = pre ? ps * m * m : 0.0f;                                  \
            PM[i]  = pre ? pp * m * m : m;                                     \
            m_[c] = m; tl_[c] = tail;                                          \
        }                                                                      \
        if (t0 + 3 >= f) {                                                     \
            _Pragma("unroll")                                                  \
            for (int c = 0; c < 4; ++c) {                                      \
                const int i = ((gg) << 2) + c;                                 \
                const float an = fmaxf((&an4.x)[c], MIN_SPEECH);               \
                const float cand = fminf(fmaxf(an * __expf((&lr4.x)[c]),       \
                                     MIN_SPEECH), an * MAX_EXPAND) * m_[c];    \
                a_cs += cand * tl_[c];                                         \
                SC1[i] += cand * tl_[c] * m_[c];                               \
            }                                                                  \
        }                                                                      \
        unsigned kk0 = 0u, kk1 = 0u;                                           \
        _Pragma("unroll")                                                      \
        for (int c = 0; c < 4; ++c) {                                          \
            const float s = (fmaxf((&pw4.x)[c], 0.0f)                          \
                             + BIAS_W * (MIN_BW + fmaxf((&bl4.x)[c], 0.0f)))   \
                            * m_[c];                                           \
            const unsigned key = (unsigned)fminf(s * KSCALE, 65535.0f);        \
            atomicAdd(&hist[wave][key >> 8], 1u);                              \
            if (c < 2) kk0 |= key << (16 * c);                                 \
            else       kk1 |= key << (16 * (c - 2));                           \
        }                                                                      \
        uint2 w2; w2.x = kk0; w2.y = kk1;                                      \
        *reinterpret_cast<uint2*>(&ku[t0 >> 1]) = w2;                          \
    }

// (512,2): 128-VGPR budget so the 2-deep pipeline (14 float4 bufs + 32-float
// state) fits without spill. 16 waves/CU — wave count proven non-binding
// (rounds 5 vs 6). Occupancy is deliberately traded for loads-in-flight.
__global__ __launch_bounds__(NTH, 2) void srp_kernel(
    const float* __restrict__ g_anchor,
    const float* __restrict__ g_lr,
    const float* __restrict__ g_pw,
    const float* __restrict__ g_bl,
    const float* __restrict__ g_mask,
    const float* __restrict__ g_sbud,
    const float* __restrict__ g_pbud,
    const float* __restrict__ g_psp,
    const float* __restrict__ g_ppa,
    const int*  __restrict__ g_front,
    float* __restrict__ g_out,
    int n_rows)
{
    constexpr float MIN_SPEECH = 1.0f;
    constexpr float MAX_EXPAND = 3.0f;
    constexpr float MIN_BW = 0.1f;
    constexpr float BIAS_W = 0.15f;
    constexpr float INV_TEMP = 1.0f / 0.12f;

    __shared__ unsigned ku[T_DIM / 2];          // 16 KB: packed 16-bit keys
    __shared__ unsigned hist[NWAVE][256];       // 8 KB: per-wave histograms
    __shared__ unsigned s_tot[256];
    __shared__ float wred[NWAVE][4];
    __shared__ float s_scal[6];
    __shared__ unsigned sh_hb, sh_k1, sh_lb, sh_k2;

    const int b = blockIdx.x;
    const int tid = threadIdx.x;
    const int wave = tid >> 6;
    const int lane = tid & 63;
    const long long row = (long long)b * T_DIM;
    const int f = g_front[b];

    // zero this wave's own histogram (wave-private -> no barrier needed)
    #pragma unroll
    for (int d = 0; d < 4; ++d) hist[wave][lane + 64 * d] = 0u;

    // Per-thread state:
    //  SC1[i]: pre? ps*m^2 : cand*tail*m        (speech value pre-scale)
    //  PM[i]:  pre? pp*m^2 : m                  (pause prefix output, or mask;
    //          pass 2 overwrites tail entries with tc*tail*m)
    float SC1[16];
    float PM[16];
    float a_ps = 0.f, a_pp = 0.f, a_ts = 0.f, a_cs = 0.f;

    // ---------- Pass 1: 2-deep software-pipelined, unphased loads ----------
    {
        float4 Amk, Aps, App, Aan, Alr, Apw, Abl;
        float4 Bmk, Bps, Bpp, Ban, Blr, Bpw, Bbl;
        LOADG(0, Amk, Aps, App, Aan, Alr, Apw, Abl);
        LOADG(1, Bmk, Bps, Bpp, Ban, Blr, Bpw, Bbl);
        COMPUTE(0, Amk, Aps, App, Aan, Alr, Apw, Abl);
        LOADG(2, Amk, Aps, App, Aan, Alr, Apw, Abl);
        COMPUTE(1, Bmk, Bps, Bpp, Ban, Blr, Bpw, Bbl);
        LOADG(3, Bmk, Bps, Bpp, Ban, Blr, Bpw, Bbl);
        COMPUTE(2, Amk, Aps, App, Aan, Alr, Apw, Abl);
        COMPUTE(3, Bmk, Bps, Bpp, Ban, Blr, Bpw, Bbl);
    }

    // wave-level reduce of the 4 accumulators
    #pragma unroll
    for (int o = 32; o > 0; o >>= 1) {
        a_ps += __shfl_down(a_ps, o, 64);
        a_pp += __shfl_down(a_pp, o, 64);
        a_ts += __shfl_down(a_ts, o, 64);
        a_cs += __shfl_down(a_cs, o, 64);
    }
    if (lane == 0) {
        wred[wave][0] = a_ps; wred[wave][1] = a_pp;
        wred[wave][2] = a_ts; wred[wave][3] = a_cs;
    }
    __syncthreads();                                                    // B1

    if (tid < 256) {
        unsigned s = 0;
        #pragma unroll
        for (int w = 0; w < NWAVE; ++w) s += hist[w][tid];
        s_tot[tid] = s;
    }
    if (tid == 0) {
        float ps = 0.f, pp = 0.f, ts = 0.f, cs = 0.f;
        for (int w = 0; w < NWAVE; ++w) {
            ps += wred[w][0]; pp += wred[w][1];
            ts += wred[w][2]; cs += wred[w][3];
        }
        const float sb = fmaxf(g_sbud[b], ps + ts * MIN_SPEECH);
        const float pb = fmaxf(g_pbud[b], pp);
        const float rem_s = sb - ps;
        const float cts = fmaxf(cs, 1e-6f);
        s_scal[0] = (ts > 0.0f && rem_s > 0.0f) ? (rem_s / cts) : 0.0f;  // scale_s
        s_scal[1] = fmaxf(pb - pp, 0.0f);                                // rem_p
        s_scal[2] = ts;
        s_scal[3] = fmaxf(ts, 1.0f);
    }
    __syncthreads();                                                    // B2

    // wave0 scans pass-A first so the other waves' speech stores overlap it
    if (wave == 0) scan_top256(s_tot, KEEP_K, lane, &sh_hb, &sh_k1);

    // ---- early speech store: only needs scale_s; overlaps the selection ----
    {
        const float scale_s = s_scal[0];
        #pragma unroll
        for (int g = 0; g < GROUPS; ++g) {
            const int t0 = g * 2048 + (tid << 2);
            nt4 vs;
            #pragma unroll
            for (int c = 0; c < 4; ++c) {
                const int i = (g << 2) + c;
                const int t = t0 + c;
                vs[c] = (t < f) ? SC1[i] : SC1[i] * scale_s;
            }
            __builtin_nontemporal_store(vs, reinterpret_cast<nt4*>(g_out + row + t0));
        }
    }
    // re-zero own histogram for pass B
    #pragma unroll
    for (int d = 0; d < 4; ++d) hist[wave][lane + 64 * d] = 0u;
    __syncthreads();                                                    // B3

    // ---------- Pass B: low-byte histogram within selected high-byte bucket ----------
    const unsigned hb = sh_hb;
    #pragma unroll
    for (int g = 0; g < GROUPS; ++g) {
        const int t0 = g * 2048 + (tid << 2);
        const uint2 w2 = *reinterpret_cast<const uint2*>(&ku[t0 >> 1]);
        const unsigned k0 = w2.x & 0xFFFFu, k1 = w2.x >> 16;
        const unsigned k2 = w2.y & 0xFFFFu, k3 = w2.y >> 16;
        if ((k0 >> 8) == hb) atomicAdd(&hist[wave][k0 & 0xFFu], 1u);
        if ((k1 >> 8) == hb) atomicAdd(&hist[wave][k1 & 0xFFu], 1u);
        if ((k2 >> 8) == hb) atomicAdd(&hist[wave][k2 & 0xFFu], 1u);
        if ((k3 >> 8) == hb) atomicAdd(&hist[wave][k3 & 0xFFu], 1u);
    }
    __syncthreads();                                                    // B4
    if (tid < 256) {
        unsigned s = 0;
        #pragma unroll
        for (int w = 0; w < NWAVE; ++w) s += hist[w][tid];
        s_tot[tid] = s;
    }
    __syncthreads();                                                    // B5
    if (wave == 0) scan_top256(s_tot, sh_k1, lane, &sh_lb, &sh_k2);
    __syncthreads();                                                    // B6

    const float thr = (float)((sh_hb << 8) | sh_lb) * INV_KSCALE;

    // ---------- Pass 2: gated denominator (scores reconstructed from keys) ----------
    // Only tail elements (t >= f) contribute; prefix work skipped entirely.
    const float inv_ts6 = 1e-6f / s_scal[3];
    float a_d = 0.0f;
    #pragma unroll
    for (int g = 0; g < GROUPS; ++g) {
        const int t0 = g * 2048 + (tid << 2);
        if (t0 + 3 < f) continue;   // whole group is prefix
        const uint2 w2 = *reinterpret_cast<const uint2*>(&ku[t0 >> 1]);
        const unsigned kk[4] = { w2.x & 0xFFFFu, w2.x >> 16, w2.y & 0xFFFFu, w2.y >> 16 };
        #pragma unroll
        for (int c = 0; c < 4; ++c) {
            const int i = (g << 2) + c;
            const int t = t0 + c;
            if (t >= f) {
                const float m = PM[i];                     // tail = m (pre==0)
                const float s = (float)kk[c] * INV_KSCALE;
                const float gate = 1.0f / (1.0f + __expf(-(s - thr) * INV_TEMP));
                const float tc = s * gate * m * m + m * inv_ts6;   // tail_cand
                a_d += tc * m;                             // tc * tail
                PM[i] = tc * m * m;                        // tc * tail * m
            }
        }
    }
    #pragma unroll
    for (int o = 32; o > 0; o >>= 1) a_d += __shfl_down(a_d, o, 64);
    if (lane == 0) wred[wave][0] = a_d;
    __syncthreads();                                                    // B7
    if (tid == 0) {
        float d = 0.f;
        for (int w = 0; w < NWAVE; ++w) d += wred[w][0];
        const float denom = fmaxf(d, 1e-6f);
        const float ts = s_scal[2];
        const float rem_p = s_scal[1];
        s_scal[4] = (ts > 0.0f && rem_p > 0.0f) ? (rem_p / denom) : 0.0f;  // scale_p
    }
    __syncthreads();                                                    // B8

    // ---------- pause store ----------
    const float scale_p = s_scal[4];
    const long long out_off = (long long)n_rows * T_DIM;
    #pragma unroll
    for (int g = 0; g < GROUPS; ++g) {
        const int t0 = g * 2048 + (tid << 2);
        nt4 vp;
        #pragma unroll
        for (int c = 0; c < 4; ++c) {
            const int i = (g << 2) + c;
            const int t = t0 + c;
            vp[c] = (t < f) ? PM[i] : PM[i] * scale_p;
        }
        __builtin_nontemporal_store(vp, reinterpret_cast<nt4*>(g_out + out_off + row + t0));
    }
}

extern "C" void kernel_launch(void* const* d_in, const int* in_sizes, int n_in,
                              void* d_out, int out_size, void* d_ws, size_t ws_size,
                              hipStream_t stream) {
    const float* anchor = (const float*)d_in[0];
    const float* lr     = (const float*)d_in[1];
    const float* pw     = (const float*)d_in[2];
    const float* bl     = (const float*)d_in[3];
    const float* mask   = (const float*)d_in[4];
    const float* sbud   = (const float*)d_in[5];
    const float* pbud   = (const float*)d_in[6];
    const float* psp    = (const float*)d_in[7];
    const float* ppa    = (const float*)d_in[8];
    const int*   front  = (const int*)d_in[9];
    float* out = (float*)d_out;
    const int B = in_sizes[5];   // speech_budget_win has B elements
    srp_kernel<<<B, NTH, 0, stream>>>(anchor, lr, pw, bl, mask, sbud, pbud,
                                      psp, ppa, front, out, B);
}

// Round 10
// 159.346 us; speedup vs baseline: 1.0335x; 1.0148x over previous
//
#include <hip/hip_runtime.h>

#define T_DIM 8192
#define NTH 512
#define NWAVE 8
#define GROUPS 4
#define KEEP_K 2867                 // max(1, round(8192 * 0.35))
#define KSCALE 32768.0f             // 16-bit fixed-point key scale (scores < 2.0)
#define INV_KSCALE (1.0f / 32768.0f)

typedef float nt4 __attribute__((ext_vector_type(4)));  // native vec for nontemporal store

// Scan 256-bin histogram from the top, find digit where cumulative count
// reaches k. Executed by wave 0 only.
__device__ __forceinline__ void scan_top256(const unsigned* bins, unsigned k, int lane,
                                            unsigned* sh_digit, unsigned* sh_k) {
    const int r0 = lane * 4;
    const unsigned c0 = bins[255 - r0];
    const unsigned c1 = bins[255 - (r0 + 1)];
    const unsigned c2 = bins[255 - (r0 + 2)];
    const unsigned c3 = bins[255 - (r0 + 3)];
    const unsigned s1 = c0 + c1, s2 = s1 + c2, s3 = s2 + c3;
    unsigned tot = s3;
    #pragma unroll
    for (int off = 1; off < 64; off <<= 1) {
        const unsigned n = __shfl_up(tot, off, 64);
        if (lane >= off) tot += n;
    }
    const unsigned excl = tot - s3;
    const unsigned Pc[4] = { excl + c0, excl + s1, excl + s2, excl + s3 };
    unsigned prev = excl;
    #pragma unroll
    for (int c = 0; c < 4; ++c) {
        if (Pc[c] >= k && prev < k) {
            *sh_digit = (unsigned)(255 - (r0 + c));
            *sh_k = k - prev;
        }
        prev = Pc[c];
    }
}

// Issue ALL live streams of group gg back-to-back (unphased -> max loads in
// flight). Skipped regions (round-5 traffic win) get benign constants so the
// unguarded parts of compute stay NaN-free.
#define LOADG(gg, mk4, ps4, pp4, an4, lr4, pw4, bl4)                           \
    {                                                                          \
        const int t0 = (gg) * 2048 + (tid << 2);                               \
        mk4 = *reinterpret_cast<const float4*>(g_mask + row + t0);             \
        ps4 = make_float4(0.f, 0.f, 0.f, 0.f);                                 \
        pp4 = make_float4(0.f, 0.f, 0.f, 0.f);                                 \
        an4 = make_float4(1.f, 1.f, 1.f, 1.f);                                 \
        lr4 = make_float4(0.f, 0.f, 0.f, 0.f);                                 \
        if (t0 < f) {                                                          \
            ps4 = *reinterpret_cast<const float4*>(g_psp + row + t0);          \
            pp4 = *reinterpret_cast<const float4*>(g_ppa + row + t0);          \
        }                                                                      \
        if (t0 + 3 >= f) {                                                     \
            an4 = *reinterpret_cast<const float4*>(g_anchor + row + t0);       \
            lr4 = *reinterpret_cast<const float4*>(g_lr + row + t0);           \
        }                                                                      \
        pw4 = *reinterpret_cast<const float4*>(g_pw + row + t0);               \
        bl4 = *reinterpret_cast<const float4*>(g_bl + row + t0);               \
    }

// Consume one group's buffers; identical math/order to the round-5 kernel.
#define COMPUTE(gg, mk4, ps4, pp4, an4, lr4, pw4, bl4)                         \
    {                                                                          \
        const int t0 = (gg) * 2048 + (tid << 2);                               \
        float m_[4], tl_[4];                                                   \
        _Pragma("unroll")                                                      \
        for (int c = 0; c < 4; ++c) {                                          \
            const int i = ((gg) << 2) + c;                                     \
            const int t = t0 + c;                                              \
            const float m = (&mk4.x)[c];                                       \
            const bool pre = (t < f);                                          \
            const float tail = pre ? 0.0f : m;                                 \
            const float ps = (&ps4.x)[c];                                      \
            const float pp = (&pp4.x)[c];                                      \
            if (pre) { a_ps += ps * m; a_pp += pp * m; }                       \
            a_ts += tail;                                                      \
            SC1[i] = pre ? ps * m * m : 0.0f;                                  \
            PM[i]  = pre ? pp * m * m : m;                                     \
            m_[c] = m; tl_[c] = tail;                                          \
        }                                                                      \
        if (t0 + 3 >= f) {                                                     \
            _Pragma("unroll")                                                  \
            for (int c = 0; c < 4; ++c) {                                      \
                const int i = ((gg) << 2) + c;                                 \
                const float an = fmaxf((&an4.x)[c], MIN_SPEECH);               \
                const float cand = fminf(fmaxf(an * __expf((&lr4.x)[c]),       \
                                     MIN_SPEECH), an * MAX_EXPAND) * m_[c];    \
                a_cs += cand * tl_[c];                                         \
                SC1[i] += cand * tl_[c] * m_[c];                               \
            }                                                                  \
        }                                                                      \
        unsigned kk0 = 0u, kk1 = 0u;                                           \
        _Pragma("unroll")                                                      \
        for (int c = 0; c < 4; ++c) {                                          \
            const float s = (fmaxf((&pw4.x)[c], 0.0f)                          \
                             + BIAS_W * (MIN_BW + fmaxf((&bl4.x)[c], 0.0f)))   \
                            * m_[c];                                           \
            const unsigned key = (unsigned)fminf(s * KSCALE, 65535.0f);        \
            atomicAdd(&hist[wave][key >> 8], 1u);                              \
            if (c < 2) kk0 |= key << (16 * c);                                 \
            else       kk1 |= key << (16 * (c - 2));                           \
        }                                                                      \
        uint2 w2; w2.x = kk0; w2.y = kk1;                                      \
        *reinterpret_cast<uint2*>(&ku[t0 >> 1]) = w2;                          \
    }

// (512,2): 128-VGPR budget so the forced 2-deep pipeline (14 float4 bufs +
// 32-float state) fits without spill. 16 waves/CU — wave count proven
// non-binding (rounds 5 vs 6). Occupancy traded for loads-in-flight.
__global__ __launch_bounds__(NTH, 2) void srp_kernel(
    const float* __restrict__ g_anchor,
    const float* __restrict__ g_lr,
    const float* __restrict__ g_pw,
    const float* __restrict__ g_bl,
    const float* __restrict__ g_mask,
    const float* __restrict__ g_sbud,
    const float* __restrict__ g_pbud,
    const float* __restrict__ g_psp,
    const float* __restrict__ g_ppa,
    const int*  __restrict__ g_front,
    float* __restrict__ g_out,
    int n_rows)
{
    constexpr float MIN_SPEECH = 1.0f;
    constexpr float MAX_EXPAND = 3.0f;
    constexpr float MIN_BW = 0.1f;
    constexpr float BIAS_W = 0.15f;
    constexpr float INV_TEMP = 1.0f / 0.12f;

    __shared__ unsigned ku[T_DIM / 2];          // 16 KB: packed 16-bit keys
    __shared__ unsigned hist[NWAVE][256];       // 8 KB: per-wave histograms
    __shared__ unsigned s_tot[256];
    __shared__ float wred[NWAVE][4];
    __shared__ float s_scal[6];
    __shared__ unsigned sh_hb, sh_k1, sh_lb, sh_k2;

    const int b = blockIdx.x;
    const int tid = threadIdx.x;
    const int wave = tid >> 6;
    const int lane = tid & 63;
    const long long row = (long long)b * T_DIM;
    const int f = g_front[b];

    // zero this wave's own histogram (wave-private -> no barrier needed)
    #pragma unroll
    for (int d = 0; d < 4; ++d) hist[wave][lane + 64 * d] = 0u;

    // Per-thread state:
    //  SC1[i]: pre? ps*m^2 : cand*tail*m        (speech value pre-scale)
    //  PM[i]:  pre? pp*m^2 : m                  (pause prefix output, or mask;
    //          pass 2 overwrites tail entries with tc*tail*m)
    float SC1[16];
    float PM[16];
    float a_ps = 0.f, a_pp = 0.f, a_ts = 0.f, a_cs = 0.f;

    // ---------- Pass 1: 2-deep pipeline, PINNED with sched_barrier ----------
    // Round-9 evidence: without pins the scheduler sinks LOADG(g+1) below
    // COMPUTE(g) (VGPR=60, not ~100) and MLP collapses to the phased level.
    // sched_barrier(0) forbids motion across, so >=14 loads are outstanding
    // when the first compute's waitcnt hits.
    {
        float4 Amk, Aps, App, Aan, Alr, Apw, Abl;
        float4 Bmk, Bps, Bpp, Ban, Blr, Bpw, Bbl;
        LOADG(0, Amk, Aps, App, Aan, Alr, Apw, Abl);
        LOADG(1, Bmk, Bps, Bpp, Ban, Blr, Bpw, Bbl);
        __builtin_amdgcn_sched_barrier(0);
        COMPUTE(0, Amk, Aps, App, Aan, Alr, Apw, Abl);
        LOADG(2, Amk, Aps, App, Aan, Alr, Apw, Abl);
        __builtin_amdgcn_sched_barrier(0);
        COMPUTE(1, Bmk, Bps, Bpp, Ban, Blr, Bpw, Bbl);
        LOADG(3, Bmk, Bps, Bpp, Ban, Blr, Bpw, Bbl);
        __builtin_amdgcn_sched_barrier(0);
        COMPUTE(2, Amk, Aps, App, Aan, Alr, Apw, Abl);
        COMPUTE(3, Bmk, Bps, Bpp, Ban, Blr, Bpw, Bbl);
    }

    // wave-level reduce of the 4 accumulators
    #pragma unroll
    for (int o = 32; o > 0; o >>= 1) {
        a_ps += __shfl_down(a_ps, o, 64);
        a_pp += __shfl_down(a_pp, o, 64);
        a_ts += __shfl_down(a_ts, o, 64);
        a_cs += __shfl_down(a_cs, o, 64);
    }
    if (lane == 0) {
        wred[wave][0] = a_ps; wred[wave][1] = a_pp;
        wred[wave][2] = a_ts; wred[wave][3] = a_cs;
    }
    __syncthreads();                                                    // B1

    if (tid < 256) {
        unsigned s = 0;
        #pragma unroll
        for (int w = 0; w < NWAVE; ++w) s += hist[w][tid];
        s_tot[tid] = s;
    }
    if (tid == 0) {
        float ps = 0.f, pp = 0.f, ts = 0.f, cs = 0.f;
        for (int w = 0; w < NWAVE; ++w) {
            ps += wred[w][0]; pp += wred[w][1];
            ts += wred[w][2]; cs += wred[w][3];
        }
        const float sb = fmaxf(g_sbud[b], ps + ts * MIN_SPEECH);
        const float pb = fmaxf(g_pbud[b], pp);
        const float rem_s = sb - ps;
        const float cts = fmaxf(cs, 1e-6f);
        s_scal[0] = (ts > 0.0f && rem_s > 0.0f) ? (rem_s / cts) : 0.0f;  // scale_s
        s_scal[1] = fmaxf(pb - pp, 0.0f);                                // rem_p
        s_scal[2] = ts;
        s_scal[3] = fmaxf(ts, 1.0f);
    }
    __syncthreads();                                                    // B2

    // wave0 scans pass-A first so the other waves' speech stores overlap it
    if (wave == 0) scan_top256(s_tot, KEEP_K, lane, &sh_hb, &sh_k1);

    // ---- early speech store: only needs scale_s; overlaps the selection ----
    {
        const float scale_s = s_scal[0];
        #pragma unroll
        for (int g = 0; g < GROUPS; ++g) {
            const int t0 = g * 2048 + (tid << 2);
            nt4 vs;
            #pragma unroll
            for (int c = 0; c < 4; ++c) {
                const int i = (g << 2) + c;
                const int t = t0 + c;
                vs[c] = (t < f) ? SC1[i] : SC1[i] * scale_s;
            }
            __builtin_nontemporal_store(vs, reinterpret_cast<nt4*>(g_out + row + t0));
        }
    }
    // re-zero own histogram for pass B
    #pragma unroll
    for (int d = 0; d < 4; ++d) hist[wave][lane + 64 * d] = 0u;
    __syncthreads();                                                    // B3

    // ---------- Pass B: low-byte histogram within selected high-byte bucket ----------
    const unsigned hb = sh_hb;
    #pragma unroll
    for (int g = 0; g < GROUPS; ++g) {
        const int t0 = g * 2048 + (tid << 2);
        const uint2 w2 = *reinterpret_cast<const uint2*>(&ku[t0 >> 1]);
        const unsigned k0 = w2.x & 0xFFFFu, k1 = w2.x >> 16;
        const unsigned k2 = w2.y & 0xFFFFu, k3 = w2.y >> 16;
        if ((k0 >> 8) == hb) atomicAdd(&hist[wave][k0 & 0xFFu], 1u);
        if ((k1 >> 8) == hb) atomicAdd(&hist[wave][k1 & 0xFFu], 1u);
        if ((k2 >> 8) == hb) atomicAdd(&hist[wave][k2 & 0xFFu], 1u);
        if ((k3 >> 8) == hb) atomicAdd(&hist[wave][k3 & 0xFFu], 1u);
    }
    __syncthreads();                                                    // B4
    if (tid < 256) {
        unsigned s = 0;
        #pragma unroll
        for (int w = 0; w < NWAVE; ++w) s += hist[w][tid];
        s_tot[tid] = s;
    }
    __syncthreads();                                                    // B5
    if (wave == 0) scan_top256(s_tot, sh_k1, lane, &sh_lb, &sh_k2);
    __syncthreads();                                                    // B6

    const float thr = (float)((sh_hb << 8) | sh_lb) * INV_KSCALE;

    // ---------- Pass 2: gated denominator (scores reconstructed from keys) ----------
    // Only tail elements (t >= f) contribute; prefix work skipped entirely.
    const float inv_ts6 = 1e-6f / s_scal[3];
    float a_d = 0.0f;
    #pragma unroll
    for (int g = 0; g < GROUPS; ++g) {
        const int t0 = g * 2048 + (tid << 2);
        if (t0 + 3 < f) continue;   // whole group is prefix
        const uint2 w2 = *reinterpret_cast<const uint2*>(&ku[t0 >> 1]);
        const unsigned kk[4] = { w2.x & 0xFFFFu, w2.x >> 16, w2.y & 0xFFFFu, w2.y >> 16 };
        #pragma unroll
        for (int c = 0; c < 4; ++c) {
            const int i = (g << 2) + c;
            const int t = t0 + c;
            if (t >= f) {
                const float m = PM[i];                     // tail = m (pre==0)
                const float s = (float)kk[c] * INV_KSCALE;
                const float gate = 1.0f / (1.0f + __expf(-(s - thr) * INV_TEMP));
                const float tc = s * gate * m * m + m * inv_ts6;   // tail_cand
                a_d += tc * m;                             // tc * tail
                PM[i] = tc * m * m;                        // tc * tail * m
            }
        }
    }
    #pragma unroll
    for (int o = 32; o > 0; o >>= 1) a_d += __shfl_down(a_d, o, 64);
    if (lane == 0) wred[wave][0] = a_d;
    __syncthreads();                                                    // B7
    if (tid == 0) {
        float d = 0.f;
        for (int w = 0; w < NWAVE; ++w) d += wred[w][0];
        const float denom = fmaxf(d, 1e-6f);
        const float ts = s_scal[2];
        const float rem_p = s_scal[1];
        s_scal[4] = (ts > 0.0f && rem_p > 0.0f) ? (rem_p / denom) : 0.0f;  // scale_p
    }
    __syncthreads();                                                    // B8

    // ---------- pause store ----------
    const float scale_p = s_scal[4];
    const long long out_off = (long long)n_rows * T_DIM;
    #pragma unroll
    for (int g = 0; g < GROUPS; ++g) {
        const int t0 = g * 2048 + (tid << 2);
        nt4 vp;
        #pragma unroll
        for (int c = 0; c < 4; ++c) {
            const int i = (g << 2) + c;
            const int t = t0 + c;
            vp[c] = (t < f) ? PM[i] : PM[i] * scale_p;
        }
        __builtin_nontemporal_store(vp, reinterpret_cast<nt4*>(g_out + out_off + row + t0));
    }
}

extern "C" void kernel_launch(void* const* d_in, const int* in_sizes, int n_in,
                              void* d_out, int out_size, void* d_ws, size_t ws_size,
                              hipStream_t stream) {
    const float* anchor = (const float*)d_in[0];
    const float* lr     = (const float*)d_in[1];
    const float* pw     = (const float*)d_in[2];
    const float* bl     = (const float*)d_in[3];
    const float* mask   = (const float*)d_in[4];
    const float* sbud   = (const float*)d_in[5];
    const float* pbud   = (const float*)d_in[6];
    const float* psp    = (const float*)d_in[7];
    const float* ppa    = (const float*)d_in[8];
    const int*   front  = (const int*)d_in[9];
    float* out = (float*)d_out;
    const int B = in_sizes[5];   // speech_budget_win has B elements
    srp_kernel<<<B, NTH, 0, stream>>>(anchor, lr, pw, bl, mask, sbud, pbud,
                                      psp, ppa, front, out, B);
}